// Round 14
// baseline (3609.506 us; speedup 1.0000x reference)
//
#include <hip/hip_runtime.h>
#include <math.h>

static constexpr int B_ = 4, S_ = 2048, D_ = 1024, CH_ = 64, N_ = 32;
static constexpr float EPS_ = 1.1920929e-07f;
static constexpr float C2_  = 2.0f / 262144.0f;   // 2/(B*CH*D)
static constexpr int GRID_ = 128;                 // scan grid (1 block/CU, co-resident)

typedef __attribute__((ext_vector_type(8))) short bf16x8;
typedef __attribute__((ext_vector_type(4))) short bf16x4;
typedef __attribute__((ext_vector_type(4))) float f32x4;

__device__ __forceinline__ float sigf(float x)  { return 1.f/(1.f+expf(-x)); }
__device__ __forceinline__ float siluf(float x) { return x/(1.f+expf(-x)); }
__device__ __forceinline__ float silugrad(float x){
  float s = 1.f/(1.f+expf(-x));
  return s*(1.f + x*(1.f-s));
}
__device__ __forceinline__ short f2b(float f){
  union{float f;unsigned u;}c; c.f=f;
  unsigned u=c.u;
  return (short)((u + 0x7fffu + ((u>>16)&1u)) >> 16);   // RNE
}
__device__ __forceinline__ float b2f(short h){
  union{unsigned u;float f;}c; c.u=((unsigned)(unsigned short)h)<<16; return c.f;
}

// counted vmcnt wait: c = in-flight stages beyond the one we need (0..6)
template<int LPS>
__device__ __forceinline__ void wait_vm(int c){
  switch(c){
    case 0: asm volatile("s_waitcnt vmcnt(0)" ::: "memory"); break;
    case 1: asm volatile("s_waitcnt vmcnt(%0)" :: "i"(1*LPS) : "memory"); break;
    case 2: asm volatile("s_waitcnt vmcnt(%0)" :: "i"(2*LPS) : "memory"); break;
    case 3: asm volatile("s_waitcnt vmcnt(%0)" :: "i"(3*LPS) : "memory"); break;
    case 4: asm volatile("s_waitcnt vmcnt(%0)" :: "i"(4*LPS) : "memory"); break;
    case 5: asm volatile("s_waitcnt vmcnt(%0)" :: "i"(5*LPS) : "memory"); break;
    default: asm volatile("s_waitcnt vmcnt(%0)" :: "i"(6*LPS) : "memory"); break;
  }
}

// ============ scan GEMM core (4 waves, 2x2): C[m,n] = sum_k A[m,k]*B[n,k] ============
// block tile MT x NT, BK=64, DEPTH-buffered LDS, counted vmcnt + raw s_barrier.
// Source-side chunk swizzle sc = cc ^ (row&7), matching read swizzle. Result in acc.
template<int MT, int NT, int DEPTH>
__device__ __forceinline__ void score(
    const short* __restrict__ A, const short* __restrict__ Bm,
    int K, int lda, int ldb, int bm0, int bn0, short* stg,
    f32x4 (&acc)[MT/32][NT/32])
{
  constexpr int MF = MT/32, NF = NT/32;
  constexpr int ACH = MT*8, BCH = NT*8, T = 256;
  constexpr int BUF = (MT+NT)*64;
  constexpr int LPS = (ACH+BCH)/T;
  const int tid = threadIdx.x, lane = tid & 63, w = tid >> 6;
  const int wm = w>>1, wn = w&1, lrow = lane & 15, lk8 = lane >> 4;

  #pragma unroll
  for (int i=0;i<MF;++i)
    #pragma unroll
    for (int j=0;j<NF;++j) acc[i][j] = (f32x4){0.f,0.f,0.f,0.f};

  auto stage = [&](int s){
    short* la = stg + (s & (DEPTH-1))*BUF;
    short* lb = la + MT*64;
    const int k0 = s*64;
    #pragma unroll
    for (int i=tid; i<ACH; i+=T){
      int row = i>>3, sc = (i&7) ^ (row&7);
      const short* src = A + (size_t)(bm0+row)*lda + k0 + (sc<<3);
      __builtin_amdgcn_global_load_lds(
        (const __attribute__((address_space(1))) void*)src,
        (__attribute__((address_space(3))) void*)(la + i*8), 16, 0, 0);
    }
    #pragma unroll
    for (int i=tid; i<BCH; i+=T){
      int row = i>>3, sc = (i&7) ^ (row&7);
      const short* src = Bm + (size_t)(bn0+row)*ldb + k0 + (sc<<3);
      __builtin_amdgcn_global_load_lds(
        (const __attribute__((address_space(1))) void*)src,
        (__attribute__((address_space(3))) void*)(lb + i*8), 16, 0, 0);
    }
  };

  const int nk = K >> 6;
  for (int s=0; s<DEPTH-1 && s<nk; ++s) stage(s);
  for (int ks=0; ks<nk; ++ks){
    int C = nk - ks; if (C > DEPTH-1) C = DEPTH-1;
    wait_vm<LPS>(C-1);
    __builtin_amdgcn_s_barrier();
    __builtin_amdgcn_sched_barrier(0);
    if (ks + DEPTH-1 < nk) stage(ks + DEPTH-1);
    short* la = stg + (ks & (DEPTH-1))*BUF;
    short* lb = la + MT*64;
    #pragma unroll
    for (int kk=0; kk<2; ++kk){
      bf16x8 af[MF], bfr[NF];
      #pragma unroll
      for (int mi=0;mi<MF;++mi){
        int row = wm*(MT/2) + mi*16 + lrow;
        int ch = row*8 + ((kk*4+lk8) ^ (row&7));
        af[mi] = *(const bf16x8*)(la + ch*8);
      }
      #pragma unroll
      for (int ni=0;ni<NF;++ni){
        int row = wn*(NT/2) + ni*16 + lrow;
        int ch = row*8 + ((kk*4+lk8) ^ (row&7));
        bfr[ni] = *(const bf16x8*)(lb + ch*8);
      }
      #pragma unroll
      for (int mi=0;mi<MF;++mi)
        #pragma unroll
        for (int ni=0;ni<NF;++ni)
          acc[mi][ni] = __builtin_amdgcn_mfma_f32_16x16x32_bf16(af[mi], bfr[ni], acc[mi][ni], 0,0,0);
    }
  }
}

// ============ prologue GEMM (functor epilogue, DEPTH=2) ============
template<int WMW, int WNW, int DEPTH, class Epi>
__device__ __forceinline__ void gemm_core(
    const short* __restrict__ A, const short* __restrict__ Bm,
    int K, int lda, int ldb, int bm0, int bn0, short* lds, Epi epi)
{
  constexpr int BK = 64, CPR = 8;
  constexpr int BMR = WMW*64, BNR = WNW*64, T = WMW*WNW*64;
  constexpr int ACH = BMR*CPR, BCH = BNR*CPR;
  constexpr int BUF = (BMR+BNR)*BK;
  constexpr int LPS = (ACH+BCH)/T;
  const int tid = threadIdx.x, lane = tid & 63, w = tid >> 6;
  const int wm = w / WNW, wn = w % WNW, lrow = lane & 15, lk8 = lane >> 4;

  f32x4 acc[4][4];
  #pragma unroll
  for (int i=0;i<4;++i)
    #pragma unroll
    for (int j=0;j<4;++j) acc[i][j] = (f32x4){0.f,0.f,0.f,0.f};

  auto stage = [&](int s){
    short* la = lds + (s & (DEPTH-1))*BUF;
    short* lb = la + BMR*BK;
    const int k0 = s*BK;
    #pragma unroll
    for (int i=tid; i<ACH; i+=T){
      int row = i>>3, sc = (i&7) ^ (row&7);
      const short* src = A + (size_t)(bm0+row)*lda + k0 + (sc<<3);
      __builtin_amdgcn_global_load_lds(
        (const __attribute__((address_space(1))) void*)src,
        (__attribute__((address_space(3))) void*)(la + i*8), 16, 0, 0);
    }
    #pragma unroll
    for (int i=tid; i<BCH; i+=T){
      int row = i>>3, sc = (i&7) ^ (row&7);
      const short* src = Bm + (size_t)(bn0+row)*ldb + k0 + (sc<<3);
      __builtin_amdgcn_global_load_lds(
        (const __attribute__((address_space(1))) void*)src,
        (__attribute__((address_space(3))) void*)(lb + i*8), 16, 0, 0);
    }
  };

  const int nk = K >> 6;
  for (int s=0; s<DEPTH-1 && s<nk; ++s) stage(s);
  for (int ks=0; ks<nk; ++ks){
    int C = nk - ks; if (C > DEPTH-1) C = DEPTH-1;
    wait_vm<LPS>(C-1);
    __builtin_amdgcn_s_barrier();
    __builtin_amdgcn_sched_barrier(0);
    if (ks + DEPTH-1 < nk) stage(ks + DEPTH-1);
    short* la = lds + (ks & (DEPTH-1))*BUF;
    short* lb = la + BMR*BK;
    #pragma unroll
    for (int kk=0; kk<2; ++kk){
      bf16x8 af[4], bfr[4];
      #pragma unroll
      for (int mi=0;mi<4;++mi){
        int row = wm*64 + mi*16 + lrow;
        int ch = row*8 + ((kk*4+lk8) ^ (row&7));
        af[mi] = *(const bf16x8*)(la + ch*8);
      }
      #pragma unroll
      for (int ni=0;ni<4;++ni){
        int row = wn*64 + ni*16 + lrow;
        int ch = row*8 + ((kk*4+lk8) ^ (row&7));
        bfr[ni] = *(const bf16x8*)(lb + ch*8);
      }
      #pragma unroll
      for (int mi=0;mi<4;++mi)
        #pragma unroll
        for (int ni=0;ni<4;++ni)
          acc[mi][ni] = __builtin_amdgcn_mfma_f32_16x16x32_bf16(af[mi], bfr[ni], acc[mi][ni], 0,0,0);
    }
  }
  #pragma unroll
  for (int mi=0;mi<4;++mi)
    #pragma unroll
    for (int ni=0;ni<4;++ni)
      epi(bm0 + wm*64 + mi*16 + lk8*4, bn0 + wn*64 + ni*16 + lrow, acc[mi][ni]);
}

struct EpiOut { float* C;
  __device__ void operator()(int r0,int c,f32x4 q) const {
    #pragma unroll
    for (int j=0;j<4;++j) C[(size_t)(r0+j)*D_+c]=q[j]; } };

struct EpiStoreBf { short* C;
  __device__ void operator()(int r0,int c,f32x4 q) const {
    #pragma unroll
    for (int j=0;j<4;++j) C[(size_t)(r0+j)*D_+c]=f2b(q[j]); } };

struct EpiBiasSig { float* C; const float* bias;
  __device__ void operator()(int r0,int c,f32x4 q) const {
    #pragma unroll
    for (int j=0;j<4;++j) C[(size_t)(r0+j)*D_+c] = sigf(q[j] + bias[c]); } };

struct EpiScat { short* dst; int part;   // -1: v[N,256,D]; 0: q rows; 1: k rows of qk[N,512,D]
  __device__ void operator()(int r0,int c,f32x4 q) const {
    #pragma unroll
    for (int j=0;j<4;++j){
      int r = r0+j;
      int b = r >> 11, s = r & 2047, t = s >> 6, ch = s & 63;
      short sv = f2b(siluf(q[j]));
      if (part < 0) dst[((size_t)t*256 +             b*64 + ch)*D_ + c] = sv;
      else          dst[((size_t)t*512 + part*256 + b*64 + ch)*D_ + c] = sv;
    } } };

template<int WMW, int WNW, class Epi>
__global__ __launch_bounds__(WMW*WNW*64)
void mgemm(const short* __restrict__ A, const short* __restrict__ Bm,
           int K, int lda, int ldb, Epi epi){
  __shared__ __align__(16) short lds[2*(WMW+WNW)*64*64];
  gemm_core<WMW,WNW,2>(A, Bm, K, lda, ldb, blockIdx.y*WMW*64, blockIdx.x*WNW*64, lds, epi);
}

// ---------------- grid barrier: flag-array arrive + central publish (r10 protocol) ----------------
__device__ __forceinline__ void gsync(int* flags, int ep, bool do_rel, bool do_acq){
  asm volatile("s_waitcnt vmcnt(0) lgkmcnt(0)" ::: "memory");
  __syncthreads();
  const int bid = blockIdx.x, tid = threadIdx.x;
  int* rel = flags + 2048;
  if (tid == 0){
    if (do_rel) __builtin_amdgcn_fence(__ATOMIC_RELEASE, "agent");   // wbl2 + drain
    __hip_atomic_store(&flags[bid*16], ep, __ATOMIC_RELAXED, __HIP_MEMORY_SCOPE_SYSTEM);
  }
  if (bid == 0){
    if (tid < 64){
      for(;;){
        int a = __hip_atomic_load(&flags[tid*16],      __ATOMIC_RELAXED, __HIP_MEMORY_SCOPE_SYSTEM);
        int b = __hip_atomic_load(&flags[(tid+64)*16], __ATOMIC_RELAXED, __HIP_MEMORY_SCOPE_SYSTEM);
        if (__all(a >= ep && b >= ep)) break;
        __builtin_amdgcn_s_sleep(1);
      }
    }
    __syncthreads();
    if (tid == 0)
      __hip_atomic_store(rel, ep, __ATOMIC_RELAXED, __HIP_MEMORY_SCOPE_SYSTEM);
  }
  if (tid == 0){
    if (bid != 0)
      while (__hip_atomic_load(rel, __ATOMIC_RELAXED, __HIP_MEMORY_SCOPE_SYSTEM) < ep)
        __builtin_amdgcn_s_sleep(1);
    if (do_acq) __builtin_amdgcn_fence(__ATOMIC_ACQUIRE, "agent");  // inv clean L1/L2
  }
  __syncthreads();
}

// ---------------- persistent scan (r10 structure): 256 thr, 4 phases, W+S masters in regs --------
// r13 lesson: redundant dh1 unbalances phase CD -> keep r10's 4 balanced phases.
// New vs r10: fp32 W master moved LDS->registers (each thread only ever touches its own
// 16 quads; static indexing), freeing 67.6 KB LDS -> staging DEPTH 4->8 (64x64 phases)
// and 2->4 (128x128 updates) for deeper latency hiding after the acquire-inv.
__global__ __launch_bounds__(256)
void scan_coop(const short* __restrict__ qk, const short* __restrict__ vbuf,
               const short* __restrict__ ktT, const float* __restrict__ gates,
               short* __restrict__ preout, short* __restrict__ sgT,
               short* __restrict__ abuf, short* __restrict__ akT,
               short* __restrict__ dpred, short* __restrict__ dpredT, short* __restrict__ dh1T,
               const float* __restrict__ W0f, const float* __restrict__ W1f,
               short* __restrict__ W0b, short* __restrict__ W1b,
               short* __restrict__ W1bT0, short* __restrict__ W1bT1,
               int* __restrict__ bar)
{
  __shared__ __align__(16) short stg[65536];      // 128 KB staging
  const int bid = blockIdx.x;
  const int tid = threadIdx.x, lane = tid & 63, w = tid >> 6;
  const int wm = w>>1, wn = w&1, lrow = lane & 15, lk8 = lane >> 4;
  int ep = 0;

  const bool ownW1 = bid < 64;
  const int ob = ownW1 ? bid : bid - 64;
  const int obm = (ob>>3)<<7, obn = (ob&7)<<7;
  const float* Wsrc = ownW1 ? W1f : W0f;

  // fp32 masters in registers: W + S, 16 quads each (static indexing only)
  f32x4 wReg[4][4], sReg[4][4];
  #pragma unroll
  for (int mi=0;mi<4;++mi)
    #pragma unroll
    for (int ni=0;ni<4;++ni){
      int rl = wm*64 + mi*16 + lk8*4;            // bm-dim (local)
      int cl = wn*64 + ni*16 + lrow;             // bn-dim (local)
      wReg[mi][ni] = *(const f32x4*)&Wsrc[(size_t)(obn+cl)*D_ + obm + rl];
      sReg[mi][ni] = (f32x4){0.f,0.f,0.f,0.f};
    }

  const int pbm0 = (bid>>4)<<6, pbn0 = (bid&15)<<6;   // bn-major: W-panel per XCD

  for (int t=0; t<N_; ++t){
    const short* qkt = qk + (size_t)t*512*D_;
    const float al = gates[t], th = gates[N_+t], et = gates[2*N_+t];
    short* W1Tcur = (t&1) ? W1bT1 : W1bT0;
    short* W1Tnxt = (t&1) ? W1bT0 : W1bT1;

    // ---- Phase A: h = [q;k] @ W0^T -> abuf=silu(h); k rows -> akT,sgT ----
    {
      f32x4 acc[2][2];
      score<64,64,8>(qkt, W0b, 1024, 1024, 1024, pbm0, pbn0, stg, acc);
      #pragma unroll
      for (int mi=0;mi<2;++mi)
        #pragma unroll
        for (int ni=0;ni<2;++ni){
          int r0 = pbm0 + wm*32 + mi*16 + lk8*4;
          int c  = pbn0 + wn*32 + ni*16 + lrow;
          f32x4 q = acc[mi][ni];
          bf16x4 a4, g4;
          #pragma unroll
          for (int j=0;j<4;++j){
            a4[j] = f2b(siluf(q[j]));
            g4[j] = f2b(silugrad(q[j]));
            abuf[(size_t)(r0+j)*D_+c] = a4[j];
          }
          if (r0 >= 256){ int rr = r0-256;
            *(bf16x4*)&akT[(size_t)c*256+rr] = a4;
            *(bf16x4*)&sgT[(size_t)c*256+rr] = g4; }
        }
    }
    gsync(bar, ++ep, true, true);

    // ---- Phase B: pred = a @ W1^T -> preout (q rows) + dpred/dpredT (k rows) ----
    {
      const short* vt = vbuf + (size_t)t*256*D_;
      f32x4 acc[2][2];
      score<64,64,8>(abuf, W1b, 1024, 1024, 1024, pbm0, pbn0, stg, acc);
      #pragma unroll
      for (int mi=0;mi<2;++mi)
        #pragma unroll
        for (int ni=0;ni<2;++ni){
          int r0 = pbm0 + wm*32 + mi*16 + lk8*4;
          int c  = pbn0 + wn*32 + ni*16 + lrow;
          f32x4 q = acc[mi][ni];
          if (r0 < 256){
            #pragma unroll
            for (int j=0;j<4;++j){ int r=r0+j, b=r>>6, ch=r&63;
              preout[((size_t)b*S_ + t*CH_ + ch)*D_ + c] = f2b(q[j]); }
          } else { int rr = r0-256;
            bf16x4 d4;
            #pragma unroll
            for (int j=0;j<4;++j){
              float dv = C2_*(q[j] - b2f(vt[(size_t)(rr+j)*D_+c]));
              d4[j] = f2b(dv);
              dpred[(size_t)(rr+j)*D_+c] = d4[j];
            }
            *(bf16x4*)&dpredT[(size_t)c*256+rr] = d4; }
        }
    }
    if (t == N_-1) break;   // last step: retrieval only
    gsync(bar, ++ep, true, true);

    // ---- Phase C: W1-owners update W1 (g1T = akT x dpredT); W0-owners compute dh1T ----
    if (ownW1){
      f32x4 acc[4][4];
      score<128,128,4>(akT, dpredT, 256, 256, 256, obm, obn, stg, acc);
      #pragma unroll
      for (int mi=0;mi<4;++mi)
        #pragma unroll
        for (int ni=0;ni<4;++ni){
          int rl = wm*64 + mi*16 + lk8*4;        // h (local)
          int cl = wn*64 + ni*16 + lrow;         // o (local)
          f32x4 w4 = wReg[mi][ni];
          f32x4 s4 = sReg[mi][ni];
          bf16x4 nb;
          #pragma unroll
          for (int j=0;j<4;++j){
            float sv = et*s4[j] - th*acc[mi][ni][j];
            s4[j] = sv;
            float wv = (1.f-al)*w4[j] + sv;
            w4[j] = wv; nb[j] = f2b(wv);
          }
          sReg[mi][ni] = s4;
          wReg[mi][ni] = w4;
          int r0 = obm + rl, c = obn + cl;
          *(bf16x4*)&W1b[(size_t)c*D_ + r0] = nb;
          #pragma unroll
          for (int j=0;j<4;++j) W1Tnxt[(size_t)(r0+j)*D_ + c] = nb[j];
        }
    } else {
      int b = bid - 64;
      int bm0 = (b&15)<<6, bn0 = (b>>4)<<6;      // rows=h (16 tiles), cols=r (4 tiles)
      f32x4 acc[2][2];
      score<64,64,8>(W1Tcur, dpred, 1024, 1024, 1024, bm0, bn0, stg, acc);
      #pragma unroll
      for (int mi=0;mi<2;++mi)
        #pragma unroll
        for (int ni=0;ni<2;++ni){
          int r0 = bm0 + wm*32 + mi*16 + lk8*4;
          int c  = bn0 + wn*32 + ni*16 + lrow;
          #pragma unroll
          for (int j=0;j<4;++j){
            size_t i = (size_t)(r0+j)*256 + c;
            dh1T[i] = f2b(acc[mi][ni][j] * b2f(sgT[i]));
          }
        }
    }
    // C->D: only dh1T is read in D; W1-owners defer wbl2 to D->A', read nothing in D.
    gsync(bar, ++ep, !ownW1, !ownW1);

    // ---- Phase D: W0-owners update W0 (g0T = ktT x dh1T) ----
    if (!ownW1){
      f32x4 acc[4][4];
      score<128,128,4>(ktT + (size_t)t*D_*256, dh1T, 256, 256, 256, obm, obn, stg, acc);
      #pragma unroll
      for (int mi=0;mi<4;++mi)
        #pragma unroll
        for (int ni=0;ni<4;++ni){
          int rl = wm*64 + mi*16 + lk8*4;        // i (local)
          int cl = wn*64 + ni*16 + lrow;         // h (local)
          f32x4 w4 = wReg[mi][ni];
          f32x4 s4 = sReg[mi][ni];
          bf16x4 nb;
          #pragma unroll
          for (int j=0;j<4;++j){
            float sv = et*s4[j] - th*acc[mi][ni][j];
            s4[j] = sv;
            float wv = (1.f-al)*w4[j] + sv;
            w4[j] = wv; nb[j] = f2b(wv);
          }
          sReg[mi][ni] = s4;
          wReg[mi][ni] = w4;
          int r0 = obm + rl, c = obn + cl;
          *(bf16x4*)&W0b[(size_t)c*D_ + r0] = nb;
        }
    }
    gsync(bar, ++ep, true, true);   // W1-owners flush deferred C writes here
  }
}

// ---------------- small kernels ----------------
__device__ __forceinline__ float block_sum(float v){
  #pragma unroll
  for (int o=32;o>0;o>>=1) v += __shfl_down(v,o,64);
  __shared__ float sm4[4];
  int lane = threadIdx.x & 63, w = threadIdx.x >> 6;
  if (lane==0) sm4[w]=v;
  __syncthreads();
  float r = sm4[0]+sm4[1]+sm4[2]+sm4[3];
  __syncthreads();
  return r;
}

__global__ void conv_k(const float* __restrict__ s, short* __restrict__ d, int n4){
  int i = blockIdx.x*256 + threadIdx.x;
  if (i >= n4) return;
  float4 v = ((const float4*)s)[i];
  bf16x4 o = { f2b(v.x), f2b(v.y), f2b(v.z), f2b(v.w) };
  ((bf16x4*)d)[i] = o;
}

__global__ __launch_bounds__(256)
void transpose_bf_k(const short* __restrict__ in, short* __restrict__ out,
                    int R, int C, size_t ibs, size_t obs){
  __shared__ short t[64][68];
  const short* ip = in + blockIdx.z*ibs;
  short* op = out + blockIdx.z*obs;
  int r0 = blockIdx.y*64, c0 = blockIdx.x*64;
  for (int i=threadIdx.x; i<1024; i+=256){
    int r = i>>4, c4 = (i&15)*4;
    *(bf16x4*)&t[r][c4] = *(const bf16x4*)&ip[(size_t)(r0+r)*C + c0+c4];
  }
  __syncthreads();
  for (int i=threadIdx.x; i<1024; i+=256){
    int c = i>>4, r4 = (i&15)*4;
    bf16x4 v = { t[r4+0][c], t[r4+1][c], t[r4+2][c], t[r4+3][c] };
    *(bf16x4*)&op[(size_t)(c0+c)*R + r0+r4] = v;
  }
}

__global__ __launch_bounds__(256)
void transpose_f2b_k(const float* __restrict__ in, short* __restrict__ out,
                     int R, int C, size_t ibs, size_t obs){
  __shared__ short t[64][68];
  const float* ip = in + blockIdx.z*ibs;
  short* op = out + blockIdx.z*obs;
  int r0 = blockIdx.y*64, c0 = blockIdx.x*64;
  for (int i=threadIdx.x; i<1024; i+=256){
    int r = i>>4, c4 = (i&15)*4;
    float4 v = *(const float4*)&ip[(size_t)(r0+r)*C + c0+c4];
    t[r][c4+0]=f2b(v.x); t[r][c4+1]=f2b(v.y); t[r][c4+2]=f2b(v.z); t[r][c4+3]=f2b(v.w);
  }
  __syncthreads();
  for (int i=threadIdx.x; i<1024; i+=256){
    int c = i>>4, r4 = (i&15)*4;
    bf16x4 v = { t[r4+0][c], t[r4+1][c], t[r4+2][c], t[r4+3][c] };
    *(bf16x4*)&op[(size_t)(c0+c)*R + r0+r4] = v;
  }
}

__global__ void chunk_mean_k(const float* __restrict__ x, short* __restrict__ cm){
  int idx = blockIdx.x*256 + threadIdx.x;     // B*N*D = 131072
  int d  = idx & (D_-1);
  int bn = idx >> 10;
  int b = bn >> 5, n = bn & 31;
  const float* p = x + ((size_t)b*S_ + n*CH_)*D_ + d;
  float s = 0.f;
  for (int ch=0; ch<CH_; ++ch) s += p[(size_t)ch*D_];
  cm[idx] = f2b(s * (1.f/CH_));
}

__global__ void gate_reduce_k(const float* __restrict__ Z, float* __restrict__ outp, float scale){
  int n = blockIdx.x;
  float s = 0.f;
  for (int b=0;b<B_;++b){
    const float* row = Z + (size_t)(b*N_+n)*D_;
    for (int j=threadIdx.x; j<D_; j+=256) s += row[j];
  }
  float tot = block_sum(s);
  if (threadIdx.x==0) outp[n] = scale * tot / (float)(B_*D_);
}

__global__ void rmsnorm2_k(const float* __restrict__ x, const float* __restrict__ gs,
                           const float* __restrict__ gr, short* __restrict__ xs, short* __restrict__ xr){
  size_t row = blockIdx.x;
  const float* xp = x + row*D_;
  float s = 0.f;
  for (int j=threadIdx.x;j<D_;j+=256){ float v=xp[j]; s+=v*v; }
  float tot = block_sum(s);
  float rinv = rsqrtf(tot/(float)D_ + EPS_);
  for (int j=threadIdx.x;j<D_;j+=256){
    float v = xp[j]*rinv;
    xs[row*D_+j] = f2b(v*gs[j]);
    xr[row*D_+j] = f2b(v*gr[j]);
  }
}

__global__ void l2norm_b(short* __restrict__ qk){
  size_t row = blockIdx.x;
  short* p = qk + row*D_;
  float s = 0.f;
  for (int j=threadIdx.x;j<D_;j+=256){ float v=b2f(p[j]); s+=v*v; }
  float tot = block_sum(s);
  float inv = 1.f / fmaxf(sqrtf(tot), 1e-12f);
  for (int j=threadIdx.x;j<D_;j+=256) p[j] = f2b(b2f(p[j])*inv);
}

__global__ void init_state_k(const float* __restrict__ W0, const float* __restrict__ W1,
                             short* __restrict__ W0b, short* __restrict__ W1b,
                             int* __restrict__ bar){
  size_t i = (size_t)blockIdx.x*256 + threadIdx.x;
  W0b[i]=f2b(W0[i]); W1b[i]=f2b(W1[i]);
  if (i < 4096) bar[i] = 0;   // flag array (128 x 16-int stride) + rel word
}

// ---------------- host ----------------
extern "C" void kernel_launch(void* const* d_in, const int* in_sizes, int n_in,
                              void* d_out, int out_size, void* d_ws, size_t ws_size,
                              hipStream_t stream) {
  (void)in_sizes; (void)n_in; (void)out_size;
  const float* x    = (const float*)d_in[0];
  const float* Mmet = (const float*)d_in[1];
  const float* Wk   = (const float*)d_in[2];
  const float* Wv   = (const float*)d_in[3];
  const float* Wq   = (const float*)d_in[4];
  const float* Wo   = (const float*)d_in[5];
  const float* Wgd  = (const float*)d_in[6];
  const float* bgd  = (const float*)d_in[7];
  const float* Wgl  = (const float*)d_in[8];
  const float* bgl  = (const float*)d_in[9];
  const float* Wgm  = (const float*)d_in[10];
  const float* bgm  = (const float*)d_in[11];
  const float* g_store = (const float*)d_in[12];
  const float* g_retr  = (const float*)d_in[13];
  const float* W0   = (const float*)d_in[14];
  const float* W1   = (const float*)d_in[15];
  float* out = (float*)d_out;

  if (ws_size < 145000000ull) return;
  short* qk    = (short*)d_ws;          // [N,512,D] q rows 0..255, k rows 256..511
  short* vbuf  = qk    + 16777216;      // [N,256,D]
  short* xs    = vbuf  + 8388608;       // [B*S,D]
  short* xr    = xs    + 8388608;       // [B*S,D]  -> reused as ktT [N,1024,256]
  short* t1    = xr    + 8388608;       // [B*S,D]  -> reused as preout
  short* cm    = t1    + 8388608;       // [128,D]
  short* Wkb   = cm    + 131072;
  short* Wvb   = Wkb   + 1048576;
  short* Wqb   = Wvb   + 1048576;
  short* Wob   = Wqb   + 1048576;
  short* Wgdb  = Wob   + 1048576;
  short* Wglb  = Wgdb  + 1048576;
  short* Wgmb  = Wglb  + 1048576;
  short* MmetT = Wgmb  + 1048576;       // [B,D,D] transposed (bf16)
  short* W0b   = MmetT + 4194304;
  short* W1b   = W0b   + 1048576;
  short* W1bT0 = W1b   + 1048576;
  short* W1bT1 = W1bT0 + 1048576;
  short* abuf  = W1bT1 + 1048576;       // [512,D]
  short* akT   = abuf  + 524288;        // [D,256]
  short* sgT   = akT   + 262144;        // [D,256] silu'(h_k) bf16
  short* dpred = sgT   + 262144;        // [256,D]
  short* dpredT= dpred + 262144;        // [D,256]
  short* dh1T  = dpredT+ 262144;        // [D,256]
  float* Zg    = (float*)(dh1T + 262144);  // [128,D]
  float* gates = Zg    + 131072;        // [96]
  int*   bar   = (int*)(gates + 128);   // 4096 ints: flags[128*16] + rel
  short* ktT   = xr;                    // alias (xr dead before ktT written)
  short* preout= t1;                    // alias (t1 dead before scan)

  // conversions / init / static transposes
  conv_k<<<1024,256,0,stream>>>(Wk,  Wkb,  262144);
  conv_k<<<1024,256,0,stream>>>(Wv,  Wvb,  262144);
  conv_k<<<1024,256,0,stream>>>(Wq,  Wqb,  262144);
  conv_k<<<1024,256,0,stream>>>(Wo,  Wob,  262144);
  conv_k<<<1024,256,0,stream>>>(Wgd, Wgdb, 262144);
  conv_k<<<1024,256,0,stream>>>(Wgl, Wglb, 262144);
  conv_k<<<1024,256,0,stream>>>(Wgm, Wgmb, 262144);
  transpose_f2b_k<<<dim3(16,16,4),256,0,stream>>>(Mmet, MmetT, 1024, 1024, 1048576, 1048576);
  init_state_k<<<4096,256,0,stream>>>(W0, W1, W0b, W1b, bar);
  transpose_bf_k<<<dim3(16,16,1),256,0,stream>>>(W1b, W1bT0, 1024, 1024, 0, 0);

  // chunk means + gates
  chunk_mean_k<<<512,256,0,stream>>>(x, cm);
  {
    dim3 g(8,1);
    mgemm<2,2,EpiBiasSig><<<g,256,0,stream>>>(cm, Wgdb, 1024,1024,1024, EpiBiasSig{Zg, bgd});
    gate_reduce_k<<<N_,256,0,stream>>>(Zg, gates + 0,    0.01f);   // MEM_DECAY
    mgemm<2,2,EpiBiasSig><<<g,256,0,stream>>>(cm, Wglb, 1024,1024,1024, EpiBiasSig{Zg, bgl});
    gate_reduce_k<<<N_,256,0,stream>>>(Zg, gates + N_,   0.1f);    // MEM_LR
    mgemm<2,2,EpiBiasSig><<<g,256,0,stream>>>(cm, Wgmb, 1024,1024,1024, EpiBiasSig{Zg, bgm});
    gate_reduce_k<<<N_,256,0,stream>>>(Zg, gates + 2*N_, 0.9f);    // MEM_MOM
  }
  // dual RMSNorm
  rmsnorm2_k<<<B_*S_,256,0,stream>>>(x, g_store, g_retr, xs, xr);
  // t1 = xs @ Mmet[b]
  for (int b=0;b<B_;++b)
    mgemm<2,2,EpiStoreBf><<<dim3(8,16),256,0,stream>>>(
      xs + (size_t)b*S_*D_, MmetT + (size_t)b*D_*D_, 1024,1024,1024,
      EpiStoreBf{t1 + (size_t)b*S_*D_});
  // k, v, q projections with silu + chunk scatter
  {
    dim3 g(8,64);
    mgemm<2,2,EpiScat><<<g,256,0,stream>>>(t1, Wkb, 1024,1024,1024, EpiScat{qk, 1});
    mgemm<2,2,EpiScat><<<g,256,0,stream>>>(xs, Wvb, 1024,1024,1024, EpiScat{vbuf,-1});
    mgemm<2,2,EpiScat><<<g,256,0,stream>>>(xr, Wqb, 1024,1024,1024, EpiScat{qk, 0});
  }
  l2norm_b<<<N_*512,256,0,stream>>>(qk);
  // ktT[t][i][r] = qk[t][256+r][i]
  transpose_bf_k<<<dim3(16,4,32),256,0,stream>>>(qk + 256*1024, ktT, 256, 1024,
                                                 (size_t)512*1024, (size_t)1024*256);

  // persistent scan (256 threads/block, 4 phases, masters in registers)
  scan_coop<<<GRID_,256,0,stream>>>(qk, vbuf, ktT, gates, preout, sgT, abuf, akT,
                                    dpred, dpredT, dh1T, W0, W1,
                                    W0b, W1b, W1bT0, W1bT1, bar);

  // out = preout @ Wo^T
  mgemm<2,2,EpiOut><<<dim3(8,64),256,0,stream>>>(preout, Wob, 1024,1024,1024, EpiOut{out});
}

// Round 15
// 2197.111 us; speedup vs baseline: 1.6428x; 1.6428x over previous
//
#include <hip/hip_runtime.h>
#include <math.h>

static constexpr int B_ = 4, S_ = 2048, D_ = 1024, CH_ = 64, N_ = 32;
static constexpr float EPS_ = 1.1920929e-07f;
static constexpr float C2_  = 2.0f / 262144.0f;   // 2/(B*CH*D)
static constexpr int GRID_ = 128;                 // scan grid (1 block/CU, co-resident)

typedef __attribute__((ext_vector_type(8))) short bf16x8;
typedef __attribute__((ext_vector_type(4))) short bf16x4;
typedef __attribute__((ext_vector_type(4))) float f32x4;

__device__ __forceinline__ float sigf(float x)  { return 1.f/(1.f+expf(-x)); }
__device__ __forceinline__ float siluf(float x) { return x/(1.f+expf(-x)); }
__device__ __forceinline__ float silugrad(float x){
  float s = 1.f/(1.f+expf(-x));
  return s*(1.f + x*(1.f-s));
}
__device__ __forceinline__ short f2b(float f){
  union{float f;unsigned u;}c; c.f=f;
  unsigned u=c.u;
  return (short)((u + 0x7fffu + ((u>>16)&1u)) >> 16);   // RNE
}
__device__ __forceinline__ float b2f(short h){
  union{unsigned u;float f;}c; c.u=((unsigned)(unsigned short)h)<<16; return c.f;
}

template<int LPS>
__device__ __forceinline__ void wait_vm(int c){   // c = in-flight stages - 1
  if (c <= 0)      asm volatile("s_waitcnt vmcnt(0)" ::: "memory");
  else if (c == 1) asm volatile("s_waitcnt vmcnt(%0)" :: "i"(LPS)   : "memory");
  else             asm volatile("s_waitcnt vmcnt(%0)" :: "i"(2*LPS) : "memory");
}

// ============ scan GEMM core (4 waves, 2x2): C[m,n] = sum_k A[m,k]*B[n,k] ============
// block tile MT x NT, BK=64, DEPTH-buffered LDS, counted vmcnt + raw s_barrier.
// Source-side chunk swizzle sc = cc ^ (row&7), matching read swizzle. Result in acc.
template<int MT, int NT, int DEPTH>
__device__ __forceinline__ void score(
    const short* __restrict__ A, const short* __restrict__ Bm,
    int K, int lda, int ldb, int bm0, int bn0, short* stg,
    f32x4 (&acc)[MT/32][NT/32])
{
  constexpr int MF = MT/32, NF = NT/32;
  constexpr int ACH = MT*8, BCH = NT*8, T = 256;
  constexpr int BUF = (MT+NT)*64;
  constexpr int LPS = (ACH+BCH)/T;
  const int tid = threadIdx.x, lane = tid & 63, w = tid >> 6;
  const int wm = w>>1, wn = w&1, lrow = lane & 15, lk8 = lane >> 4;

  #pragma unroll
  for (int i=0;i<MF;++i)
    #pragma unroll
    for (int j=0;j<NF;++j) acc[i][j] = (f32x4){0.f,0.f,0.f,0.f};

  auto stage = [&](int s){
    short* la = stg + (s & (DEPTH-1))*BUF;
    short* lb = la + MT*64;
    const int k0 = s*64;
    #pragma unroll
    for (int i=tid; i<ACH; i+=T){
      int row = i>>3, sc = (i&7) ^ (row&7);
      const short* src = A + (size_t)(bm0+row)*lda + k0 + (sc<<3);
      __builtin_amdgcn_global_load_lds(
        (const __attribute__((address_space(1))) void*)src,
        (__attribute__((address_space(3))) void*)(la + i*8), 16, 0, 0);
    }
    #pragma unroll
    for (int i=tid; i<BCH; i+=T){
      int row = i>>3, sc = (i&7) ^ (row&7);
      const short* src = Bm + (size_t)(bn0+row)*ldb + k0 + (sc<<3);
      __builtin_amdgcn_global_load_lds(
        (const __attribute__((address_space(1))) void*)src,
        (__attribute__((address_space(3))) void*)(lb + i*8), 16, 0, 0);
    }
  };

  const int nk = K >> 6;
  for (int s=0; s<DEPTH-1 && s<nk; ++s) stage(s);
  for (int ks=0; ks<nk; ++ks){
    int C = nk - ks; if (C > DEPTH-1) C = DEPTH-1;
    wait_vm<LPS>(C-1);
    __builtin_amdgcn_s_barrier();
    __builtin_amdgcn_sched_barrier(0);
    if (ks + DEPTH-1 < nk) stage(ks + DEPTH-1);
    short* la = stg + (ks & (DEPTH-1))*BUF;
    short* lb = la + MT*64;
    #pragma unroll
    for (int kk=0; kk<2; ++kk){
      bf16x8 af[MF], bfr[NF];
      #pragma unroll
      for (int mi=0;mi<MF;++mi){
        int row = wm*(MT/2) + mi*16 + lrow;
        int ch = row*8 + ((kk*4+lk8) ^ (row&7));
        af[mi] = *(const bf16x8*)(la + ch*8);
      }
      #pragma unroll
      for (int ni=0;ni<NF;++ni){
        int row = wn*(NT/2) + ni*16 + lrow;
        int ch = row*8 + ((kk*4+lk8) ^ (row&7));
        bfr[ni] = *(const bf16x8*)(lb + ch*8);
      }
      #pragma unroll
      for (int mi=0;mi<MF;++mi)
        #pragma unroll
        for (int ni=0;ni<NF;++ni)
          acc[mi][ni] = __builtin_amdgcn_mfma_f32_16x16x32_bf16(af[mi], bfr[ni], acc[mi][ni], 0,0,0);
    }
  }
}

// ============ prologue GEMM (functor epilogue) ============
template<int WMW, int WNW, int DEPTH, class Epi>
__device__ __forceinline__ void gemm_core(
    const short* __restrict__ A, const short* __restrict__ Bm,
    int K, int lda, int ldb, int bm0, int bn0, short* lds, Epi epi)
{
  constexpr int BK = 64, CPR = 8;
  constexpr int BMR = WMW*64, BNR = WNW*64, T = WMW*WNW*64;
  constexpr int ACH = BMR*CPR, BCH = BNR*CPR;
  constexpr int BUF = (BMR+BNR)*BK;
  constexpr int LPS = (ACH+BCH)/T;
  const int tid = threadIdx.x, lane = tid & 63, w = tid >> 6;
  const int wm = w / WNW, wn = w % WNW, lrow = lane & 15, lk8 = lane >> 4;

  f32x4 acc[4][4];
  #pragma unroll
  for (int i=0;i<4;++i)
    #pragma unroll
    for (int j=0;j<4;++j) acc[i][j] = (f32x4){0.f,0.f,0.f,0.f};

  auto stage = [&](int s){
    short* la = lds + (s & (DEPTH-1))*BUF;
    short* lb = la + BMR*BK;
    const int k0 = s*BK;
    #pragma unroll
    for (int i=tid; i<ACH; i+=T){
      int row = i>>3, sc = (i&7) ^ (row&7);
      const short* src = A + (size_t)(bm0+row)*lda + k0 + (sc<<3);
      __builtin_amdgcn_global_load_lds(
        (const __attribute__((address_space(1))) void*)src,
        (__attribute__((address_space(3))) void*)(la + i*8), 16, 0, 0);
    }
    #pragma unroll
    for (int i=tid; i<BCH; i+=T){
      int row = i>>3, sc = (i&7) ^ (row&7);
      const short* src = Bm + (size_t)(bn0+row)*ldb + k0 + (sc<<3);
      __builtin_amdgcn_global_load_lds(
        (const __attribute__((address_space(1))) void*)src,
        (__attribute__((address_space(3))) void*)(lb + i*8), 16, 0, 0);
    }
  };

  const int nk = K >> 6;
  for (int s=0; s<DEPTH-1 && s<nk; ++s) stage(s);
  for (int ks=0; ks<nk; ++ks){
    int C = nk - ks; if (C > DEPTH-1) C = DEPTH-1;
    wait_vm<LPS>(C-1);
    __builtin_amdgcn_s_barrier();
    __builtin_amdgcn_sched_barrier(0);
    if (ks + DEPTH-1 < nk) stage(ks + DEPTH-1);
    short* la = lds + (ks & (DEPTH-1))*BUF;
    short* lb = la + BMR*BK;
    #pragma unroll
    for (int kk=0; kk<2; ++kk){
      bf16x8 af[4], bfr[4];
      #pragma unroll
      for (int mi=0;mi<4;++mi){
        int row = wm*64 + mi*16 + lrow;
        int ch = row*8 + ((kk*4+lk8) ^ (row&7));
        af[mi] = *(const bf16x8*)(la + ch*8);
      }
      #pragma unroll
      for (int ni=0;ni<4;++ni){
        int row = wn*64 + ni*16 + lrow;
        int ch = row*8 + ((kk*4+lk8) ^ (row&7));
        bfr[ni] = *(const bf16x8*)(lb + ch*8);
      }
      #pragma unroll
      for (int mi=0;mi<4;++mi)
        #pragma unroll
        for (int ni=0;ni<4;++ni)
          acc[mi][ni] = __builtin_amdgcn_mfma_f32_16x16x32_bf16(af[mi], bfr[ni], acc[mi][ni], 0,0,0);
    }
  }
  #pragma unroll
  for (int mi=0;mi<4;++mi)
    #pragma unroll
    for (int ni=0;ni<4;++ni)
      epi(bm0 + wm*64 + mi*16 + lk8*4, bn0 + wn*64 + ni*16 + lrow, acc[mi][ni]);
}

struct EpiOut { float* C;
  __device__ void operator()(int r0,int c,f32x4 q) const {
    #pragma unroll
    for (int j=0;j<4;++j) C[(size_t)(r0+j)*D_+c]=q[j]; } };

struct EpiStoreBf { short* C;
  __device__ void operator()(int r0,int c,f32x4 q) const {
    #pragma unroll
    for (int j=0;j<4;++j) C[(size_t)(r0+j)*D_+c]=f2b(q[j]); } };

struct EpiBiasSig { float* C; const float* bias;
  __device__ void operator()(int r0,int c,f32x4 q) const {
    #pragma unroll
    for (int j=0;j<4;++j) C[(size_t)(r0+j)*D_+c] = sigf(q[j] + bias[c]); } };

struct EpiScat { short* dst; int part;   // -1: v[N,256,D]; 0: q rows; 1: k rows of qk[N,512,D]
  __device__ void operator()(int r0,int c,f32x4 q) const {
    #pragma unroll
    for (int j=0;j<4;++j){
      int r = r0+j;
      int b = r >> 11, s = r & 2047, t = s >> 6, ch = s & 63;
      short sv = f2b(siluf(q[j]));
      if (part < 0) dst[((size_t)t*256 +             b*64 + ch)*D_ + c] = sv;
      else          dst[((size_t)t*512 + part*256 + b*64 + ch)*D_ + c] = sv;
    } } };

template<int WMW, int WNW, class Epi>
__global__ __launch_bounds__(WMW*WNW*64)
void mgemm(const short* __restrict__ A, const short* __restrict__ Bm,
           int K, int lda, int ldb, Epi epi){
  __shared__ __align__(16) short lds[2*(WMW+WNW)*64*64];
  gemm_core<WMW,WNW,2>(A, Bm, K, lda, ldb, blockIdx.y*WMW*64, blockIdx.x*WNW*64, lds, epi);
}

// ---------------- grid barrier: flag-array arrive + central publish (r10 protocol) ----------------
// Each leader stores its own 64B-strided flag (parallel, no line contention); block 0's wave-0
// polls all 128 flags (2 bypass loads/lane) and publishes a release word; other leaders spin on
// that single word. Leader-only wbl2 (release) / inv (acquire), skippable per phase.
__device__ __forceinline__ void gsync(int* flags, int ep, bool do_rel, bool do_acq){
  asm volatile("s_waitcnt vmcnt(0) lgkmcnt(0)" ::: "memory");
  __syncthreads();
  const int bid = blockIdx.x, tid = threadIdx.x;
  int* rel = flags + 2048;
  if (tid == 0){
    if (do_rel) __builtin_amdgcn_fence(__ATOMIC_RELEASE, "agent");   // wbl2 + drain
    __hip_atomic_store(&flags[bid*16], ep, __ATOMIC_RELAXED, __HIP_MEMORY_SCOPE_SYSTEM);
  }
  if (bid == 0){
    if (tid < 64){
      for(;;){
        int a = __hip_atomic_load(&flags[tid*16],      __ATOMIC_RELAXED, __HIP_MEMORY_SCOPE_SYSTEM);
        int b = __hip_atomic_load(&flags[(tid+64)*16], __ATOMIC_RELAXED, __HIP_MEMORY_SCOPE_SYSTEM);
        if (__all(a >= ep && b >= ep)) break;
        __builtin_amdgcn_s_sleep(1);
      }
    }
    __syncthreads();
    if (tid == 0)
      __hip_atomic_store(rel, ep, __ATOMIC_RELAXED, __HIP_MEMORY_SCOPE_SYSTEM);
  }
  if (tid == 0){
    if (bid != 0)
      while (__hip_atomic_load(rel, __ATOMIC_RELAXED, __HIP_MEMORY_SCOPE_SYSTEM) < ep)
        __builtin_amdgcn_s_sleep(1);
    if (do_acq) __builtin_amdgcn_fence(__ATOMIC_ACQUIRE, "agent");  // inv clean L1/L2
  }
  __syncthreads();
}

// ---------------- persistent scan kernel (r10): 256 threads, masters in LDS (W) + regs (S) -----
__global__ __launch_bounds__(256)
void scan_coop(const short* __restrict__ qk, const short* __restrict__ vbuf,
               const short* __restrict__ ktT, const float* __restrict__ gates,
               short* __restrict__ preout, short* __restrict__ sgT,
               short* __restrict__ abuf, short* __restrict__ akT,
               short* __restrict__ dpred, short* __restrict__ dpredT, short* __restrict__ dh1T,
               const float* __restrict__ W0f, const float* __restrict__ W1f,
               short* __restrict__ W0b, short* __restrict__ W1b,
               short* __restrict__ W1bT0, short* __restrict__ W1bT1,
               int* __restrict__ bar)
{
  __shared__ __align__(16) float wM[128*132];     // 67.6 KB fp32 W master tile [c][r]
  __shared__ __align__(16) short stg[32768];      // 64 KB staging
  const int bid = blockIdx.x;
  const int tid = threadIdx.x, lane = tid & 63, w = tid >> 6;
  const int wm = w>>1, wn = w&1, lrow = lane & 15, lk8 = lane >> 4;
  int ep = 0;

  const bool ownW1 = bid < 64;
  const int ob = ownW1 ? bid : bid - 64;
  const int obm = (ob>>3)<<7, obn = (ob&7)<<7;
  const float* Wsrc = ownW1 ? W1f : W0f;
  for (int i=tid; i<4096; i+=256){
    int cl = i>>5, r4 = (i&31)<<2;
    f32x4 v = *(const f32x4*)&Wsrc[(size_t)(obn+cl)*D_ + obm + r4];
    *(f32x4*)&wM[cl*132 + r4] = v;
  }
  f32x4 sReg[4][4];
  #pragma unroll
  for (int i=0;i<4;++i)
    #pragma unroll
    for (int j=0;j<4;++j) sReg[i][j] = (f32x4){0.f,0.f,0.f,0.f};
  __syncthreads();

  const int pbm0 = (bid>>4)<<6, pbn0 = (bid&15)<<6;   // bn-major: W-panel per XCD

  for (int t=0; t<N_; ++t){
    const short* qkt = qk + (size_t)t*512*D_;
    const float al = gates[t], th = gates[N_+t], et = gates[2*N_+t];
    short* W1Tcur = (t&1) ? W1bT1 : W1bT0;
    short* W1Tnxt = (t&1) ? W1bT0 : W1bT1;

    // ---- Phase A: h = [q;k] @ W0^T -> abuf=silu(h); k rows -> akT,sgT ----
    {
      f32x4 acc[2][2];
      score<64,64,4>(qkt, W0b, 1024, 1024, 1024, pbm0, pbn0, stg, acc);
      #pragma unroll
      for (int mi=0;mi<2;++mi)
        #pragma unroll
        for (int ni=0;ni<2;++ni){
          int r0 = pbm0 + wm*32 + mi*16 + lk8*4;
          int c  = pbn0 + wn*32 + ni*16 + lrow;
          f32x4 q = acc[mi][ni];
          bf16x4 a4, g4;
          #pragma unroll
          for (int j=0;j<4;++j){
            a4[j] = f2b(siluf(q[j]));
            g4[j] = f2b(silugrad(q[j]));
            abuf[(size_t)(r0+j)*D_+c] = a4[j];
          }
          if (r0 >= 256){ int rr = r0-256;
            *(bf16x4*)&akT[(size_t)c*256+rr] = a4;
            *(bf16x4*)&sgT[(size_t)c*256+rr] = g4; }
        }
    }
    gsync(bar, ++ep, true, true);

    // ---- Phase B: pred = a @ W1^T -> preout (q rows) + dpred/dpredT (k rows) ----
    {
      const short* vt = vbuf + (size_t)t*256*D_;
      f32x4 acc[2][2];
      score<64,64,4>(abuf, W1b, 1024, 1024, 1024, pbm0, pbn0, stg, acc);
      #pragma unroll
      for (int mi=0;mi<2;++mi)
        #pragma unroll
        for (int ni=0;ni<2;++ni){
          int r0 = pbm0 + wm*32 + mi*16 + lk8*4;
          int c  = pbn0 + wn*32 + ni*16 + lrow;
          f32x4 q = acc[mi][ni];
          if (r0 < 256){
            #pragma unroll
            for (int j=0;j<4;++j){ int r=r0+j, b=r>>6, ch=r&63;
              preout[((size_t)b*S_ + t*CH_ + ch)*D_ + c] = f2b(q[j]); }
          } else { int rr = r0-256;
            bf16x4 d4;
            #pragma unroll
            for (int j=0;j<4;++j){
              float dv = C2_*(q[j] - b2f(vt[(size_t)(rr+j)*D_+c]));
              d4[j] = f2b(dv);
              dpred[(size_t)(rr+j)*D_+c] = d4[j];
            }
            *(bf16x4*)&dpredT[(size_t)c*256+rr] = d4; }
        }
    }
    if (t == N_-1) break;   // last step: retrieval only
    gsync(bar, ++ep, true, true);

    // ---- Phase C: W1-owners update W1 (g1T = akT x dpredT); W0-owners compute dh1T ----
    if (ownW1){
      f32x4 acc[4][4];
      score<128,128,2>(akT, dpredT, 256, 256, 256, obm, obn, stg, acc);
      #pragma unroll
      for (int mi=0;mi<4;++mi)
        #pragma unroll
        for (int ni=0;ni<4;++ni){
          int rl = wm*64 + mi*16 + lk8*4;        // h (local)
          int cl = wn*64 + ni*16 + lrow;         // o (local)
          f32x4 w4 = *(f32x4*)&wM[cl*132 + rl];
          f32x4 s4 = sReg[mi][ni];
          bf16x4 nb;
          #pragma unroll
          for (int j=0;j<4;++j){
            float sv = et*s4[j] - th*acc[mi][ni][j];
            s4[j] = sv;
            float wv = (1.f-al)*w4[j] + sv;
            w4[j] = wv; nb[j] = f2b(wv);
          }
          sReg[mi][ni] = s4;
          *(f32x4*)&wM[cl*132 + rl] = w4;
          int r0 = obm + rl, c = obn + cl;
          *(bf16x4*)&W1b[(size_t)c*D_ + r0] = nb;
          #pragma unroll
          for (int j=0;j<4;++j) W1Tnxt[(size_t)(r0+j)*D_ + c] = nb[j];
        }
    } else {
      int b = bid - 64;
      int bm0 = (b&15)<<6, bn0 = (b>>4)<<6;      // rows=h (16 tiles), cols=r (4 tiles)
      f32x4 acc[2][2];
      score<64,64,4>(W1Tcur, dpred, 1024, 1024, 1024, bm0, bn0, stg, acc);
      #pragma unroll
      for (int mi=0;mi<2;++mi)
        #pragma unroll
        for (int ni=0;ni<2;++ni){
          int r0 = bm0 + wm*32 + mi*16 + lk8*4;
          int c  = bn0 + wn*32 + ni*16 + lrow;
          #pragma unroll
          for (int j=0;j<4;++j){
            size_t i = (size_t)(r0+j)*256 + c;
            dh1T[i] = f2b(acc[mi][ni][j] * b2f(sgT[i]));
          }
        }
    }
    // C->D: only dh1T is read in D; W1-owners defer wbl2 to D->A', read nothing in D.
    gsync(bar, ++ep, !ownW1, !ownW1);

    // ---- Phase D: W0-owners update W0 (g0T = ktT x dh1T) ----
    if (!ownW1){
      f32x4 acc[4][4];
      score<128,128,2>(ktT + (size_t)t*D_*256, dh1T, 256, 256, 256, obm, obn, stg, acc);
      #pragma unroll
      for (int mi=0;mi<4;++mi)
        #pragma unroll
        for (int ni=0;ni<4;++ni){
          int rl = wm*64 + mi*16 + lk8*4;        // i (local)
          int cl = wn*64 + ni*16 + lrow;         // h (local)
          f32x4 w4 = *(f32x4*)&wM[cl*132 + rl];
          f32x4 s4 = sReg[mi][ni];
          bf16x4 nb;
          #pragma unroll
          for (int j=0;j<4;++j){
            float sv = et*s4[j] - th*acc[mi][ni][j];
            s4[j] = sv;
            float wv = (1.f-al)*w4[j] + sv;
            w4[j] = wv; nb[j] = f2b(wv);
          }
          sReg[mi][ni] = s4;
          *(f32x4*)&wM[cl*132 + rl] = w4;
          int r0 = obm + rl, c = obn + cl;
          *(bf16x4*)&W0b[(size_t)c*D_ + r0] = nb;
        }
    }
    gsync(bar, ++ep, true, true);   // W1-owners flush deferred C writes here
  }
}

// ---------------- small kernels ----------------
__device__ __forceinline__ float block_sum(float v){
  #pragma unroll
  for (int o=32;o>0;o>>=1) v += __shfl_down(v,o,64);
  __shared__ float sm4[4];
  int lane = threadIdx.x & 63, w = threadIdx.x >> 6;
  if (lane==0) sm4[w]=v;
  __syncthreads();
  float r = sm4[0]+sm4[1]+sm4[2]+sm4[3];
  __syncthreads();
  return r;
}

// 7 weight matrices (1024x1024 fp32 each) -> contiguous bf16 block, one launch
__global__ __launch_bounds__(256)
void conv7_k(const float* __restrict__ s0, const float* __restrict__ s1,
             const float* __restrict__ s2, const float* __restrict__ s3,
             const float* __restrict__ s4, const float* __restrict__ s5,
             const float* __restrict__ s6, short* __restrict__ dst){
  int b = blockIdx.x;                 // 7168 blocks, 1024 per weight
  int wsel = b >> 10;
  const float* s = (wsel==0)?s0:(wsel==1)?s1:(wsel==2)?s2:(wsel==3)?s3:
                   (wsel==4)?s4:(wsel==5)?s5:s6;
  int i = (b & 1023)*256 + threadIdx.x;          // float4 index within weight
  float4 v = ((const float4*)s)[i];
  bf16x4 o = { f2b(v.x), f2b(v.y), f2b(v.z), f2b(v.w) };
  ((bf16x4*)(dst + (size_t)wsel*1048576))[i] = o;
}

__global__ __launch_bounds__(256)
void transpose_bf_k(const short* __restrict__ in, short* __restrict__ out,
                    int R, int C, size_t ibs, size_t obs){
  __shared__ short t[64][68];
  const short* ip = in + blockIdx.z*ibs;
  short* op = out + blockIdx.z*obs;
  int r0 = blockIdx.y*64, c0 = blockIdx.x*64;
  for (int i=threadIdx.x; i<1024; i+=256){
    int r = i>>4, c4 = (i&15)*4;
    *(bf16x4*)&t[r][c4] = *(const bf16x4*)&ip[(size_t)(r0+r)*C + c0+c4];
  }
  __syncthreads();
  for (int i=threadIdx.x; i<1024; i+=256){
    int c = i>>4, r4 = (i&15)*4;
    bf16x4 v = { t[r4+0][c], t[r4+1][c], t[r4+2][c], t[r4+3][c] };
    *(bf16x4*)&op[(size_t)(c0+c)*R + r0+r4] = v;
  }
}

__global__ __launch_bounds__(256)
void transpose_f2b_k(const float* __restrict__ in, short* __restrict__ out,
                     int R, int C, size_t ibs, size_t obs){
  __shared__ short t[64][68];
  const float* ip = in + blockIdx.z*ibs;
  short* op = out + blockIdx.z*obs;
  int r0 = blockIdx.y*64, c0 = blockIdx.x*64;
  for (int i=threadIdx.x; i<1024; i+=256){
    int r = i>>4, c4 = (i&15)*4;
    float4 v = *(const float4*)&ip[(size_t)(r0+r)*C + c0+c4];
    t[r][c4+0]=f2b(v.x); t[r][c4+1]=f2b(v.y); t[r][c4+2]=f2b(v.z); t[r][c4+3]=f2b(v.w);
  }
  __syncthreads();
  for (int i=threadIdx.x; i<1024; i+=256){
    int c = i>>4, r4 = (i&15)*4;
    bf16x4 v = { t[r4+0][c], t[r4+1][c], t[r4+2][c], t[r4+3][c] };
    *(bf16x4*)&op[(size_t)(c0+c)*R + r0+r4] = v;
  }
}

__global__ void chunk_mean_k(const float* __restrict__ x, short* __restrict__ cm){
  int idx = blockIdx.x*256 + threadIdx.x;     // B*N*D = 131072
  int d  = idx & (D_-1);
  int bn = idx >> 10;
  int b = bn >> 5, n = bn & 31;
  const float* p = x + ((size_t)b*S_ + n*CH_)*D_ + d;
  float s = 0.f;
  for (int ch=0; ch<CH_; ++ch) s += p[(size_t)ch*D_];
  cm[idx] = f2b(s * (1.f/CH_));
}

__global__ void gate_reduce_k(const float* __restrict__ Z, float* __restrict__ outp, float scale){
  int n = blockIdx.x;
  float s = 0.f;
  for (int b=0;b<B_;++b){
    const float* row = Z + (size_t)(b*N_+n)*D_;
    for (int j=threadIdx.x; j<D_; j+=256) s += row[j];
  }
  float tot = block_sum(s);
  if (threadIdx.x==0) outp[n] = scale * tot / (float)(B_*D_);
}

__global__ void rmsnorm2_k(const float* __restrict__ x, const float* __restrict__ gs,
                           const float* __restrict__ gr, short* __restrict__ xs, short* __restrict__ xr){
  size_t row = blockIdx.x;
  const float* xp = x + row*D_;
  float s = 0.f;
  for (int j=threadIdx.x;j<D_;j+=256){ float v=xp[j]; s+=v*v; }
  float tot = block_sum(s);
  float rinv = rsqrtf(tot/(float)D_ + EPS_);
  for (int j=threadIdx.x;j<D_;j+=256){
    float v = xp[j]*rinv;
    xs[row*D_+j] = f2b(v*gs[j]);
    xr[row*D_+j] = f2b(v*gr[j]);
  }
}

__global__ void l2norm_b(short* __restrict__ qk){
  size_t row = blockIdx.x;
  short* p = qk + row*D_;
  float s = 0.f;
  for (int j=threadIdx.x;j<D_;j+=256){ float v=b2f(p[j]); s+=v*v; }
  float tot = block_sum(s);
  float inv = 1.f / fmaxf(sqrtf(tot), 1e-12f);
  for (int j=threadIdx.x;j<D_;j+=256) p[j] = f2b(b2f(p[j])*inv);
}

__global__ void init_state_k(const float* __restrict__ W0, const float* __restrict__ W1,
                             short* __restrict__ W0b, short* __restrict__ W1b,
                             int* __restrict__ bar){
  size_t i = (size_t)blockIdx.x*256 + threadIdx.x;
  W0b[i]=f2b(W0[i]); W1b[i]=f2b(W1[i]);
  if (i < 4096) bar[i] = 0;   // flag array (128 x 16-int stride) + rel word
}

// ---------------- host ----------------
extern "C" void kernel_launch(void* const* d_in, const int* in_sizes, int n_in,
                              void* d_out, int out_size, void* d_ws, size_t ws_size,
                              hipStream_t stream) {
  (void)in_sizes; (void)n_in; (void)out_size;
  const float* x    = (const float*)d_in[0];
  const float* Mmet = (const float*)d_in[1];
  const float* Wk   = (const float*)d_in[2];
  const float* Wv   = (const float*)d_in[3];
  const float* Wq   = (const float*)d_in[4];
  const float* Wo   = (const float*)d_in[5];
  const float* Wgd  = (const float*)d_in[6];
  const float* bgd  = (const float*)d_in[7];
  const float* Wgl  = (const float*)d_in[8];
  const float* bgl  = (const float*)d_in[9];
  const float* Wgm  = (const float*)d_in[10];
  const float* bgm  = (const float*)d_in[11];
  const float* g_store = (const float*)d_in[12];
  const float* g_retr  = (const float*)d_in[13];
  const float* W0   = (const float*)d_in[14];
  const float* W1   = (const float*)d_in[15];
  float* out = (float*)d_out;

  if (ws_size < 145000000ull) return;
  short* qk    = (short*)d_ws;          // [N,512,D] q rows 0..255, k rows 256..511
  short* vbuf  = qk    + 16777216;      // [N,256,D]
  short* xs    = vbuf  + 8388608;       // [B*S,D]
  short* xr    = xs    + 8388608;       // [B*S,D]  -> reused as ktT [N,1024,256]
  short* t1    = xr    + 8388608;       // [B*S,D]  -> reused as preout
  short* cm    = t1    + 8388608;       // [128,D]
  short* Wkb   = cm    + 131072;        // 7 weights contiguous from here
  short* Wvb   = Wkb   + 1048576;
  short* Wqb   = Wvb   + 1048576;
  short* Wob   = Wqb   + 1048576;
  short* Wgdb  = Wob   + 1048576;
  short* Wglb  = Wgdb  + 1048576;
  short* Wgmb  = Wglb  + 1048576;
  short* MmetT = Wgmb  + 1048576;       // [B,D,D] transposed (bf16)
  short* W0b   = MmetT + 4194304;
  short* W1b   = W0b   + 1048576;
  short* W1bT0 = W1b   + 1048576;
  short* W1bT1 = W1bT0 + 1048576;
  short* abuf  = W1bT1 + 1048576;       // [512,D]
  short* akT   = abuf  + 524288;        // [D,256]
  short* sgT   = akT   + 262144;        // [D,256] silu'(h_k) bf16
  short* dpred = sgT   + 262144;        // [256,D]
  short* dpredT= dpred + 262144;        // [D,256]
  short* dh1T  = dpredT+ 262144;        // [D,256]
  float* Zg    = (float*)(dh1T + 262144);  // [128,D]
  float* gates = Zg    + 131072;        // [96]
  int*   bar   = (int*)(gates + 128);   // 4096 ints: flags[128*16] + rel
  short* ktT   = xr;                    // alias (xr dead before ktT written)
  short* preout= t1;                    // alias (t1 dead before scan)

  // conversions / init / static transposes
  conv7_k<<<7168,256,0,stream>>>(Wk, Wv, Wq, Wo, Wgd, Wgl, Wgm, Wkb);
  transpose_f2b_k<<<dim3(16,16,4),256,0,stream>>>(Mmet, MmetT, 1024, 1024, 1048576, 1048576);
  init_state_k<<<4096,256,0,stream>>>(W0, W1, W0b, W1b, bar);
  transpose_bf_k<<<dim3(16,16,1),256,0,stream>>>(W1b, W1bT0, 1024, 1024, 0, 0);

  // chunk means + gates
  chunk_mean_k<<<512,256,0,stream>>>(x, cm);
  {
    dim3 g(8,1);
    mgemm<2,2,EpiBiasSig><<<g,256,0,stream>>>(cm, Wgdb, 1024,1024,1024, EpiBiasSig{Zg, bgd});
    gate_reduce_k<<<N_,256,0,stream>>>(Zg, gates + 0,    0.01f);   // MEM_DECAY
    mgemm<2,2,EpiBiasSig><<<g,256,0,stream>>>(cm, Wglb, 1024,1024,1024, EpiBiasSig{Zg, bgl});
    gate_reduce_k<<<N_,256,0,stream>>>(Zg, gates + N_,   0.1f);    // MEM_LR
    mgemm<2,2,EpiBiasSig><<<g,256,0,stream>>>(cm, Wgmb, 1024,1024,1024, EpiBiasSig{Zg, bgm});
    gate_reduce_k<<<N_,256,0,stream>>>(Zg, gates + 2*N_, 0.9f);    // MEM_MOM
  }
  // dual RMSNorm
  rmsnorm2_k<<<B_*S_,256,0,stream>>>(x, g_store, g_retr, xs, xr);
  // t1 = xs @ Mmet[b]
  for (int b=0;b<B_;++b)
    mgemm<2,2,EpiStoreBf><<<dim3(8,16),256,0,stream>>>(
      xs + (size_t)b*S_*D_, MmetT + (size_t)b*D_*D_, 1024,1024,1024,
      EpiStoreBf{t1 + (size_t)b*S_*D_});
  // k, v, q projections with silu + chunk scatter
  {
    dim3 g(8,64);
    mgemm<2,2,EpiScat><<<g,256,0,stream>>>(t1, Wkb, 1024,1024,1024, EpiScat{qk, 1});
    mgemm<2,2,EpiScat><<<g,256,0,stream>>>(xs, Wvb, 1024,1024,1024, EpiScat{vbuf,-1});
    mgemm<2,2,EpiScat><<<g,256,0,stream>>>(xr, Wqb, 1024,1024,1024, EpiScat{qk, 0});
  }
  l2norm_b<<<N_*512,256,0,stream>>>(qk);
  // ktT[t][i][r] = qk[t][256+r][i]
  transpose_bf_k<<<dim3(16,4,32),256,0,stream>>>(qk + 256*1024, ktT, 256, 1024,
                                                 (size_t)512*1024, (size_t)1024*256);

  // persistent scan (256 threads/block, 4 phases)
  scan_coop<<<GRID_,256,0,stream>>>(qk, vbuf, ktT, gates, preout, sgT, abuf, akT,
                                    dpred, dpredT, dh1T, W0, W1,
                                    W0b, W1b, W1bT0, W1bT1, bar);

  // out = preout @ Wo^T
  mgemm<2,2,EpiOut><<<dim3(8,64),256,0,stream>>>(preout, Wob, 1024,1024,1024, EpiOut{out});
}